// Round 1
// baseline (542.884 us; speedup 1.0000x reference)
//
#include <hip/hip_runtime.h>
#include <hip/hip_bf16.h>
#include <math.h>

// Problem constants (N,C,H,W = 32,512,64,64; D=4, r=16)
#define N_ 32
#define C_ 512
#define HW_ 4096     // 64*64
#define D_ 4
#define RHID_ 32     // C/r
#define BLOCK_ 128   // C/D
#define C2_ 2048     // C*D

// ---------------- Kernel 1: avg+max pooling over HW per (n,c) ----------------
// grid = N_*C_ blocks, 256 threads. Each block reduces 4096 floats (16 KB).
__global__ __launch_bounds__(256) void pool_kernel(
    const float* __restrict__ x, float* __restrict__ avg_out,
    float* __restrict__ max_out) {
  const int b = blockIdx.x;  // n*C + c
  const float4* src = (const float4*)(x + (size_t)b * HW_);
  const int t = threadIdx.x;

  double dsum = 0.0;
  float mx = -INFINITY;
#pragma unroll
  for (int i = 0; i < 4; ++i) {
    float4 v = src[t + i * 256];
    dsum += (double)v.x + (double)v.y + (double)v.z + (double)v.w;
    mx = fmaxf(mx, fmaxf(fmaxf(v.x, v.y), fmaxf(v.z, v.w)));
  }
  // wave (64-lane) reduction
#pragma unroll
  for (int off = 32; off > 0; off >>= 1) {
    dsum += __shfl_down(dsum, off);
    mx = fmaxf(mx, __shfl_down(mx, off));
  }
  __shared__ double s_sum[4];
  __shared__ float s_max[4];
  const int wave = t >> 6;
  if ((t & 63) == 0) { s_sum[wave] = dsum; s_max[wave] = mx; }
  __syncthreads();
  if (t == 0) {
    double tot = s_sum[0] + s_sum[1] + s_sum[2] + s_sum[3];
    float m = fmaxf(fmaxf(s_max[0], s_max[1]), fmaxf(s_max[2], s_max[3]));
    avg_out[b] = (float)(tot * (1.0 / (double)HW_));
    max_out[b] = m;
  }
}

// ------------- Kernel 2: shared MLP + per-(n,d) top-128 indices --------------
// grid = N_*D_ = 128 blocks, 256 threads.
// logits[c] for scale d = (relu(avg@W1+b1)+relu(max@W1+b1)) @ W2[:, c*4+d] + 2*b2[c*4+d]
// top_k semantics: descending by value, ties -> smaller index first.
__global__ __launch_bounds__(256) void mlp_topk_kernel(
    const float* __restrict__ avg, const float* __restrict__ mx,
    const float* __restrict__ W1, const float* __restrict__ b1,
    const float* __restrict__ W2, const float* __restrict__ b2,
    int* __restrict__ idx_out) {
  const int n = blockIdx.x >> 2;
  const int d = blockIdx.x & 3;
  const int t = threadIdx.x;

  __shared__ float s_avg[C_];
  __shared__ float s_mx[C_];
  __shared__ double s_h[RHID_];
  __shared__ unsigned long long s_key[C_];

  // stage pooled vectors for sample n
#pragma unroll
  for (int i = 0; i < 2; ++i) {
    int c = t + i * 256;
    s_avg[c] = avg[n * C_ + c];
    s_mx[c] = mx[n * C_ + c];
  }
  __syncthreads();

  // hidden layer (fp64): 32 dots of length 512, by 32 threads
  if (t < RHID_) {
    double acc_a = (double)b1[t];
    double acc_m = acc_a;
    for (int c = 0; c < C_; ++c) {
      double w = (double)W1[c * RHID_ + t];
      acc_a += (double)s_avg[c] * w;
      acc_m += (double)s_mx[c] * w;
    }
    s_h[t] = (acc_a > 0.0 ? acc_a : 0.0) + (acc_m > 0.0 ? acc_m : 0.0);
  }
  __syncthreads();

  // logits for this scale d, packed into descending-sortable keys
  for (int c = t; c < C_; c += 256) {
    const int col = c * D_ + d;
    double acc = 2.0 * (double)b2[col];
#pragma unroll
    for (int j = 0; j < RHID_; ++j)
      acc += s_h[j] * (double)W2[j * C2_ + col];
    float f = (float)acc;
    unsigned u = __float_as_uint(f);
    u = (u & 0x80000000u) ? ~u : (u | 0x80000000u);  // order-preserving map
    // secondary key: 511-c so that descending key sort -> ascending index on ties
    s_key[c] = ((unsigned long long)u << 32) | (unsigned)(C_ - 1 - c);
  }
  __syncthreads();

  // bitonic sort, 512 elems, descending
  for (int kk = 2; kk <= C_; kk <<= 1) {
    for (int jj = kk >> 1; jj > 0; jj >>= 1) {
#pragma unroll
      for (int r = 0; r < 2; ++r) {
        int i = t + r * 256;
        int ixj = i ^ jj;
        if (ixj > i) {
          bool ddd = ((i & kk) != 0);  // descending overall
          unsigned long long a = s_key[i], b = s_key[ixj];
          if ((a > b) == ddd) { s_key[i] = b; s_key[ixj] = a; }
        }
      }
      __syncthreads();
    }
  }

  if (t < BLOCK_) {
    int c = (C_ - 1) - (int)(s_key[t] & 0xFFFFFFFFu);
    idx_out[(n * D_ + d) * BLOCK_ + t] = c;
  }
}

// ---------------- Kernel 3: gather channels per selected index ---------------
// grid = N_*C_ blocks, 256 threads. Each block copies one 16 KB channel plane.
__global__ __launch_bounds__(256) void gather_kernel(
    const float* __restrict__ x, const int* __restrict__ idx,
    float* __restrict__ out) {
  const int b = blockIdx.x;  // n*C + j
  const int n = b >> 9;
  const int c = idx[b];
  const float4* src = (const float4*)(x + ((size_t)(n * C_ + c)) * HW_);
  float4* dst = (float4*)(out + (size_t)b * HW_);
  const int t = threadIdx.x;
#pragma unroll
  for (int i = 0; i < 4; ++i) dst[t + i * 256] = src[t + i * 256];
}

extern "C" void kernel_launch(void* const* d_in, const int* in_sizes, int n_in,
                              void* d_out, int out_size, void* d_ws, size_t ws_size,
                              hipStream_t stream) {
  const float* x  = (const float*)d_in[0];
  const float* W1 = (const float*)d_in[1];
  const float* b1 = (const float*)d_in[2];
  const float* W2 = (const float*)d_in[3];
  const float* b2 = (const float*)d_in[4];
  float* out = (float*)d_out;

  // workspace layout: avg[N*C] f32 | max[N*C] f32 | idx[N*C] i32  (192 KB)
  float* ws_avg = (float*)d_ws;
  float* ws_max = ws_avg + N_ * C_;
  int* ws_idx = (int*)(ws_max + N_ * C_);

  pool_kernel<<<N_ * C_, 256, 0, stream>>>(x, ws_avg, ws_max);
  mlp_topk_kernel<<<N_ * D_, 256, 0, stream>>>(ws_avg, ws_max, W1, b1, W2, b2,
                                               ws_idx);
  gather_kernel<<<N_ * C_, 256, 0, stream>>>(x, ws_idx, out);
}